// Round 1
// baseline (4991.779 us; speedup 1.0000x reference)
//
#include <hip/hip_runtime.h>
#include <math.h>

// Problem constants
#define N_ 8
#define C_ 512
#define H_ 66
#define W_ 90
#define S_ 5940          // H_*W_
#define K9_ (C_*9)

// ---------------------------------------------------------------------------
// K1: adaptive avg pools to 1x1, 2x2, 3x3, 6x6 simultaneously.
// One block per (n,c) plane. 66x90 = (6*11) x (6*15): compute the 36 sums of
// 11x15 sub-blocks, then combine (sz=3: 2x2 of them, sz=2: 3x3, sz=1: all).
// Output layout: p0[(n*50 + off_sz + sy*sz+sx)*512 + c], offs = {1:0,2:1,3:5,6:14}
// ---------------------------------------------------------------------------
__global__ __launch_bounds__(256) void pool_kernel(const float* __restrict__ feats,
                                                   float* __restrict__ p0) {
  int nc = blockIdx.x;              // 0..4095
  int n = nc >> 9, c = nc & 511;
  const float* plane = feats + (size_t)nc * S_;
  __shared__ float partial[396];    // (row, bx): 66 rows x 6 col-blocks of 15
  for (int u = threadIdx.x; u < 396; u += 256) {
    const float* r = plane + u * 15;   // row*90 + bx*15 == u*15
    float s = 0.f;
    #pragma unroll
    for (int i = 0; i < 15; ++i) s += r[i];
    partial[u] = s;
  }
  __syncthreads();
  __shared__ float sums6[36];
  if (threadIdx.x < 36) {
    int by = threadIdx.x / 6, bx = threadIdx.x % 6;
    float s = 0.f;
    #pragma unroll
    for (int r = 0; r < 11; ++r) s += partial[(by * 11 + r) * 6 + bx];
    sums6[threadIdx.x] = s;
  }
  __syncthreads();
  int t = threadIdx.x;
  size_t base = (size_t)n * 50 * 512 + c;
  if (t < 36) {                       // sz=6
    p0[base + (size_t)(14 + t) * 512] = sums6[t] * (1.0f / 165.0f);
  } else if (t < 45) {                // sz=3 : 2x2 of 6-blocks
    int i = t - 36; int y = i / 3, x = i % 3;
    float s = sums6[(2*y)*6 + 2*x] + sums6[(2*y)*6 + 2*x + 1]
            + sums6[(2*y+1)*6 + 2*x] + sums6[(2*y+1)*6 + 2*x + 1];
    p0[base + (size_t)(5 + i) * 512] = s * (1.0f / 660.0f);
  } else if (t < 49) {                // sz=2 : 3x3 of 6-blocks
    int i = t - 45; int y = i / 2, x = i % 2;
    float s = 0.f;
    #pragma unroll
    for (int yy = 0; yy < 3; ++yy)
      #pragma unroll
      for (int xx = 0; xx < 3; ++xx) s += sums6[(3*y + yy)*6 + 3*x + xx];
    p0[base + (size_t)(1 + i) * 512] = s * (1.0f / 1485.0f);
  } else if (t == 49) {               // sz=1
    float s = 0.f;
    #pragma unroll
    for (int i = 0; i < 36; ++i) s += sums6[i];
    p0[base] = s * (1.0f / 5940.0f);
  }
}

// ---------------------------------------------------------------------------
// K2: tiny per-row GEMM: Out[rid][co] = sum_ci W[co][ci] * In[rid][ci]
// rows rid = n*50 + off + j, j < cnt, n < 8. One block per row, 512 outputs.
// ---------------------------------------------------------------------------
__global__ __launch_bounds__(256) void rowgemm(const float* __restrict__ Wm,
                                               const float* __restrict__ In,
                                               float* __restrict__ Out,
                                               int off, int cnt) {
  int b = blockIdx.x;
  int n = b / cnt, j = b % cnt;
  size_t rid = (size_t)n * 50 + off + j;
  __shared__ __align__(16) float xin[512];
  xin[threadIdx.x]       = In[rid * 512 + threadIdx.x];
  xin[threadIdx.x + 256] = In[rid * 512 + 256 + threadIdx.x];
  __syncthreads();
  int co0 = threadIdx.x, co1 = threadIdx.x + 256;
  float acc0 = 0.f, acc1 = 0.f;
  for (int ci = 0; ci < 512; ci += 4) {
    float4 xv = *(const float4*)&xin[ci];
    float4 w0 = *(const float4*)&Wm[(size_t)co0 * 512 + ci];
    float4 w1 = *(const float4*)&Wm[(size_t)co1 * 512 + ci];
    acc0 += w0.x*xv.x + w0.y*xv.y + w0.z*xv.z + w0.w*xv.w;
    acc1 += w1.x*xv.x + w1.y*xv.y + w1.z*xv.z + w1.w*xv.w;
  }
  Out[rid * 512 + co0] = acc0;
  Out[rid * 512 + co1] = acc1;
}

// ---------------------------------------------------------------------------
// K3: 1x1-conv GEMM. Out[n][co][s] = bias[co] + sum_ci W[co][ci]*In[n][ci][s]
// 64x64 tile, Ktile=16, 256 threads, 4x4 microtile. SPLIT: ci>=512 reads In1
// (virtual concat for the bott conv).
// ---------------------------------------------------------------------------
template<bool RELU, bool SPLIT>
__global__ __launch_bounds__(256) void gemm1x1(const float* __restrict__ Wm,
    const float* __restrict__ In0, const float* __restrict__ In1,
    const float* __restrict__ bias, float* __restrict__ Out, int K) {
  __shared__ __align__(16) float Wt[16][64];
  __shared__ __align__(16) float It[16][64];
  int t = threadIdx.x;
  int s0 = blockIdx.x * 64;
  int co0 = blockIdx.y * 64;
  int n = blockIdx.z;
  int coA = co0 + (t >> 2);
  int kA = (t & 3) * 4;
  int kB = t >> 4;            // 0..15
  int sB = (t & 15) * 4;      // 0..60
  int ty = t >> 4, tx = t & 15;
  float acc[4][4];
  #pragma unroll
  for (int i = 0; i < 4; ++i)
    #pragma unroll
    for (int j = 0; j < 4; ++j) acc[i][j] = 0.f;

  for (int k0 = 0; k0 < K; k0 += 16) {
    float4 w4 = *(const float4*)&Wm[(size_t)coA * K + k0 + kA];
    int kg = k0 + kB;
    const float* src = In0;
    int ci = kg;
    if (SPLIT && kg >= 512) { src = In1; ci = kg - 512; }
    int s = s0 + sB;
    float4 b4 = make_float4(0.f, 0.f, 0.f, 0.f);
    if (s < S_) b4 = *(const float4*)&src[((size_t)n * C_ + ci) * S_ + s];
    Wt[kA + 0][t >> 2] = w4.x;
    Wt[kA + 1][t >> 2] = w4.y;
    Wt[kA + 2][t >> 2] = w4.z;
    Wt[kA + 3][t >> 2] = w4.w;
    *(float4*)&It[kB][sB] = b4;
    __syncthreads();
    #pragma unroll
    for (int kk = 0; kk < 16; ++kk) {
      float4 a = *(const float4*)&Wt[kk][ty * 4];
      float4 b = *(const float4*)&It[kk][tx * 4];
      float av[4] = {a.x, a.y, a.z, a.w};
      float bv[4] = {b.x, b.y, b.z, b.w};
      #pragma unroll
      for (int i = 0; i < 4; ++i)
        #pragma unroll
        for (int j = 0; j < 4; ++j)
          acc[i][j] = fmaf(av[i], bv[j], acc[i][j]);
    }
    __syncthreads();
  }
  int s = s0 + tx * 4;
  if (s < S_) {
    #pragma unroll
    for (int i = 0; i < 4; ++i) {
      int co = co0 + ty * 4 + i;
      float bi = bias[co];
      float ov[4];
      #pragma unroll
      for (int j = 0; j < 4; ++j) {
        float v = acc[i][j] + bi;
        if (RELU) v = fmaxf(v, 0.f);
        ov[j] = v;
      }
      *(float4*)&Out[((size_t)n * C_ + co) * S_ + s] =
          make_float4(ov[0], ov[1], ov[2], ov[3]);
    }
  }
}

// ---------------------------------------------------------------------------
// K5/K7/K9: 3x3 conv as implicit GEMM (K = 512*9 = 4608). W is OIHW ->
// row-major (co, 4608). B-operand gathered on the fly with bounds checks.
// ---------------------------------------------------------------------------
template<int ST, int PAD>
__global__ __launch_bounds__(256) void conv3(const float* __restrict__ Wm,
    const float* __restrict__ In, const float* __restrict__ bias,
    float* __restrict__ Out, int IH, int IW, int OH, int OW) {
  int P = OH * OW;
  __shared__ __align__(16) float Wt[16][64];
  __shared__ __align__(16) float It[16][64];
  int t = threadIdx.x;
  int p0 = blockIdx.x * 64;
  int co0 = blockIdx.y * 64;
  int n = blockIdx.z;
  int coA = co0 + (t >> 2);
  int kA = (t & 3) * 4;
  int pl = t & 63;
  int pp = p0 + pl;
  int oy = pp / OW, ox = pp - (pp / OW) * OW;
  bool pv = pp < P;
  int ty = t >> 4, tx = t & 15;
  float acc[4][4];
  #pragma unroll
  for (int i = 0; i < 4; ++i)
    #pragma unroll
    for (int j = 0; j < 4; ++j) acc[i][j] = 0.f;

  for (int k0 = 0; k0 < K9_; k0 += 16) {
    float4 w4 = *(const float4*)&Wm[(size_t)coA * K9_ + k0 + kA];
    float bvals[4];
    #pragma unroll
    for (int r = 0; r < 4; ++r) {
      int kk = (t >> 6) + r * 4;
      int k = k0 + kk;
      int ci = k / 9;
      int rem = k - ci * 9;
      int ky = rem / 3;
      int kx = rem - ky * 3;
      int iy = oy * ST + ky - PAD;
      int ix = ox * ST + kx - PAD;
      float v = 0.f;
      if (pv && (unsigned)iy < (unsigned)IH && (unsigned)ix < (unsigned)IW)
        v = In[(((size_t)n * C_ + ci) * IH + iy) * IW + ix];
      bvals[r] = v;
    }
    Wt[kA + 0][t >> 2] = w4.x;
    Wt[kA + 1][t >> 2] = w4.y;
    Wt[kA + 2][t >> 2] = w4.z;
    Wt[kA + 3][t >> 2] = w4.w;
    #pragma unroll
    for (int r = 0; r < 4; ++r) It[(t >> 6) + r * 4][pl] = bvals[r];
    __syncthreads();
    #pragma unroll
    for (int kk = 0; kk < 16; ++kk) {
      float4 a = *(const float4*)&Wt[kk][ty * 4];
      float4 b = *(const float4*)&It[kk][tx * 4];
      float av[4] = {a.x, a.y, a.z, a.w};
      float bv[4] = {b.x, b.y, b.z, b.w};
      #pragma unroll
      for (int i = 0; i < 4; ++i)
        #pragma unroll
        for (int j = 0; j < 4; ++j)
          acc[i][j] = fmaf(av[i], bv[j], acc[i][j]);
    }
    __syncthreads();
  }
  #pragma unroll
  for (int i = 0; i < 4; ++i) {
    int co = co0 + ty * 4 + i;
    float bi = bias[co];
    #pragma unroll
    for (int j = 0; j < 4; ++j) {
      int p = p0 + tx * 4 + j;
      if (p < P) Out[((size_t)n * C_ + co) * P + p] = acc[i][j] + bi;
    }
  }
}

// ---------------------------------------------------------------------------
// K6/K8: VALID maxpool
// ---------------------------------------------------------------------------
__global__ __launch_bounds__(256) void maxpool_k(const float* __restrict__ In,
    float* __restrict__ Out, int IH, int IW, int OH, int OW, int k, int s,
    int total) {
  int idx = blockIdx.x * 256 + threadIdx.x;
  if (idx >= total) return;
  int ow = OH * OW;
  int nc = idx / ow;
  int r = idx - nc * ow;
  int oy = r / OW, ox = r - (r / OW) * OW;
  const float* base = In + ((size_t)nc * IH + oy * s) * IW + ox * s;
  float m = -INFINITY;
  for (int ky = 0; ky < k; ++ky)
    for (int kx = 0; kx < k; ++kx)
      m = fmaxf(m, base[ky * IW + kx]);
  Out[idx] = m;
}

// ---------------------------------------------------------------------------
// K4: fused parsing. Uses linearity: wgt_i = sigmoid(convF - up(wn(p_i))),
// where convF = wn_w*feats + wn_b (computed by gemm1x1).
// up = bilinear, half-pixel centers, clamped (jax.image.resize semantics).
// ---------------------------------------------------------------------------
__global__ __launch_bounds__(256) void parsing_kernel(
    const float* __restrict__ convF, const float* __restrict__ p,
    const float* __restrict__ q, float* __restrict__ out) {
  int s = blockIdx.x * 256 + threadIdx.x;
  if (s >= S_) return;
  int c = blockIdx.y;
  int n = blockIdx.z;
  int h = s / 90, w = s - (s / 90) * 90;
  size_t gidx = ((size_t)n * C_ + c) * S_ + s;
  float cf = convF[gidx];
  const int szs[4]  = {1, 2, 3, 6};
  const int offs[4] = {0, 1, 5, 14};
  float num = 0.f, den = 0.f;
  #pragma unroll
  for (int i = 0; i < 4; ++i) {
    int sz = szs[i];
    // exact sample position: ((h+0.5)*sz)/66 - 0.5 (correctly rounded, same
    // value as jax's (h+0.5)/(66/sz) since both are correctly-rounded)
    float fy = ((h + 0.5f) * sz) / 66.0f - 0.5f;
    float fl = floorf(fy);
    float tyf = fy - fl;
    int y0 = (int)fl;
    int y1 = min(y0 + 1, sz - 1);
    y0 = max(y0, 0);
    float fx = ((w + 0.5f) * sz) / 90.0f - 0.5f;
    float flx = floorf(fx);
    float txf = fx - flx;
    int x0 = (int)flx;
    int x1 = min(x0 + 1, sz - 1);
    x0 = max(x0, 0);
    size_t base = ((size_t)n * 50 + offs[i]) * 512 + c;
    int i00 = (y0 * sz + x0) * 512, i01 = (y0 * sz + x1) * 512;
    int i10 = (y1 * sz + x0) * 512, i11 = (y1 * sz + x1) * 512;
    float p00 = p[base + i00], p01 = p[base + i01];
    float p10 = p[base + i10], p11 = p[base + i11];
    float up = (p00 * (1.f - txf) + p01 * txf) * (1.f - tyf)
             + (p10 * (1.f - txf) + p11 * txf) * tyf;
    float q00 = q[base + i00], q01 = q[base + i01];
    float q10 = q[base + i10], q11 = q[base + i11];
    float qup = (q00 * (1.f - txf) + q01 * txf) * (1.f - tyf)
              + (q10 * (1.f - txf) + q11 * txf) * tyf;
    float wgt = 1.0f / (1.0f + expf(-(cf - qup)));
    num += up * wgt;
    den += wgt;
  }
  out[gidx] = num / den;
}

// ---------------------------------------------------------------------------
// K11: dynamic per-(n,c) depthwise 5x7 conv, pad (2,3).
// ---------------------------------------------------------------------------
__global__ __launch_bounds__(256) void dynconv(const float* __restrict__ inp,
    const float* __restrict__ theta, float* __restrict__ out) {
  int nc = blockIdx.y;
  __shared__ float th[35];
  if (threadIdx.x < 35) th[threadIdx.x] = theta[(size_t)nc * 35 + threadIdx.x];
  __syncthreads();
  int s = blockIdx.x * 256 + threadIdx.x;
  if (s >= S_) return;
  int h = s / 90, w = s - (s / 90) * 90;
  const float* pl = inp + (size_t)nc * S_;
  float acc = 0.f;
  #pragma unroll
  for (int ky = 0; ky < 5; ++ky) {
    int iy = h + ky - 2;
    if ((unsigned)iy >= (unsigned)H_) continue;
    #pragma unroll
    for (int kx = 0; kx < 7; ++kx) {
      int ix = w + kx - 3;
      if ((unsigned)ix >= (unsigned)W_) continue;
      acc = fmaf(th[ky * 7 + kx], pl[iy * 90 + ix], acc);
    }
  }
  out[(size_t)nc * S_ + s] = acc;
}

// ---------------------------------------------------------------------------
extern "C" void kernel_launch(void* const* d_in, const int* in_sizes, int n_in,
                              void* d_out, int out_size, void* d_ws, size_t ws_size,
                              hipStream_t stream) {
  const float* feats  = (const float*)d_in[0];
  const float* scale_w= (const float*)d_in[1];
  const float* wn_w   = (const float*)d_in[2];
  const float* wn_b   = (const float*)d_in[3];
  const float* pa_w1  = (const float*)d_in[4];
  const float* pa_b1  = (const float*)d_in[5];
  const float* pa_w2  = (const float*)d_in[6];
  const float* pa_b2  = (const float*)d_in[7];
  const float* pa_w3  = (const float*)d_in[8];
  const float* pa_b3  = (const float*)d_in[9];
  const float* u_w    = (const float*)d_in[10];
  const float* u_b    = (const float*)d_in[11];
  const float* v_w    = (const float*)d_in[12];
  const float* v_b    = (const float*)d_in[13];
  const float* bott_w = (const float*)d_in[14];
  const float* bott_b = (const float*)d_in[15];

  float* ws = (float*)d_ws;
  const size_t BIG = (size_t)N_ * C_ * S_;        // 24,330,240
  float* A    = ws;                               // convF -> inp -> pose
  float* B    = A + BIG;                          // parsing -> pose0
  float* t1   = B + BIG;                          // 8*512*32*44 = 5,767,168
  float* t2   = t1 + (size_t)N_ * C_ * 32 * 44;   // 8*512*16*22 = 1,441,792
  float* t3   = t2 + (size_t)N_ * C_ * 16 * 22;
  float* t4   = t3 + (size_t)N_ * C_ * 16 * 22;   // 8*512*35
  float* th   = t4 + (size_t)N_ * C_ * 35;        // theta, 8*512*35
  float* p0   = th + (size_t)N_ * C_ * 35;        // 8*50*512
  float* pbuf = p0 + (size_t)N_ * 50 * C_;
  float* qbuf = pbuf + (size_t)N_ * 50 * C_;
  float* outp = (float*)d_out;

  // 1) pools
  pool_kernel<<<dim3(N_ * C_), 256, 0, stream>>>(feats, p0);
  // 2) p_i = scale_w[i] * p0_i ; q_i = wn_w * p_i
  const int offs[4] = {0, 1, 5, 14};
  const int cnts[4] = {1, 4, 9, 36};
  for (int i = 0; i < 4; ++i)
    rowgemm<<<dim3(N_ * cnts[i]), 256, 0, stream>>>(
        scale_w + (size_t)i * C_ * C_, p0, pbuf, offs[i], cnts[i]);
  rowgemm<<<dim3(N_ * 50), 256, 0, stream>>>(wn_w, pbuf, qbuf, 0, 50);
  // 3) convF = wn_w*feats + wn_b -> A
  gemm1x1<false, false><<<dim3(93, 8, N_), 256, 0, stream>>>(
      wn_w, feats, nullptr, wn_b, A, 512);
  // 4) parsing -> B
  parsing_kernel<<<dim3(24, C_, N_), 256, 0, stream>>>(A, pbuf, qbuf, B);
  // 5) inp = u_w*feats + u_b -> A
  gemm1x1<false, false><<<dim3(93, 8, N_), 256, 0, stream>>>(
      u_w, feats, nullptr, u_b, A, 512);
  // 6) param adapter chain on parsing (B)
  conv3<2, 0><<<dim3(22, 8, N_), 256, 0, stream>>>(pa_w1, B, pa_b1, t1,
                                                   66, 90, 32, 44);
  maxpool_k<<<dim3((N_ * C_ * 16 * 22 + 255) / 256), 256, 0, stream>>>(
      t1, t2, 32, 44, 16, 22, 2, 2, N_ * C_ * 16 * 22);
  conv3<1, 1><<<dim3(6, 8, N_), 256, 0, stream>>>(pa_w2, t2, pa_b2, t3,
                                                  16, 22, 16, 22);
  maxpool_k<<<dim3((N_ * C_ * 5 * 7 + 255) / 256), 256, 0, stream>>>(
      t3, t4, 16, 22, 5, 7, 3, 3, N_ * C_ * 5 * 7);
  conv3<1, 1><<<dim3(1, 8, N_), 256, 0, stream>>>(pa_w3, t4, pa_b3, th,
                                                  5, 7, 5, 7);
  // 7) pose0 = dynconv(inp=A, theta) -> B
  dynconv<<<dim3(24, N_ * C_), 256, 0, stream>>>(A, th, B);
  // 8) pose = relu(v_w*pose0 + v_b) -> A
  gemm1x1<true, false><<<dim3(93, 8, N_), 256, 0, stream>>>(
      v_w, B, nullptr, v_b, A, 512);
  // 9) out = relu(bott_w * concat(pose=A, feats) + bott_b)
  gemm1x1<true, true><<<dim3(93, 8, N_), 256, 0, stream>>>(
      bott_w, A, feats, bott_b, outp, 1024);
}

// Round 6
// 2440.927 us; speedup vs baseline: 2.0450x; 2.0450x over previous
//
#include <hip/hip_runtime.h>
#include <math.h>

// Problem constants
#define N_ 8
#define C_ 512
#define H_ 66
#define W_ 90
#define S_ 5940          // H_*W_

typedef unsigned short u16;
typedef short bf16x8 __attribute__((ext_vector_type(8)));
typedef float f32x4 __attribute__((ext_vector_type(4)));

// ---- bf16 split helpers (round-to-nearest-even). x = hi + lo to ~2^-17 rel.
__device__ __forceinline__ u16 bf16_rn(float x) {
  unsigned u = __float_as_uint(x);
  return (u16)((u + 0x7fffu + ((u >> 16) & 1u)) >> 16);
}
__device__ __forceinline__ float bf16_f(u16 h) {
  return __uint_as_float(((unsigned)h) << 16);
}
__device__ __forceinline__ void split2(float v, u16& h, u16& l) {
  h = bf16_rn(v);
  l = bf16_rn(v - bf16_f(h));
}

// ---- async global->LDS, 16B per lane. LDS dest = wave-uniform base + lane*16.
typedef __attribute__((address_space(1))) const void gv_t;
typedef __attribute__((address_space(3))) void lv_t;
__device__ __forceinline__ void glds16(const void* g, void* l) {
  __builtin_amdgcn_global_load_lds((gv_t*)g, (lv_t*)l, 16, 0, 0);
}

__device__ __forceinline__ f32x4 mfma16(bf16x8 a, bf16x8 b, f32x4 c) {
  return __builtin_amdgcn_mfma_f32_16x16x32_bf16(a, b, c, 0, 0, 0);
}

// ---------------------------------------------------------------------------
// zero scratch page (redirect target for invalid global_load_lds lanes)
// ---------------------------------------------------------------------------
__global__ void zerok(u16* zb) { zb[threadIdx.x] = 0; }

// ---------------------------------------------------------------------------
// feats NCHW f32 -> [n][s][c] bf16 hi/lo (LDS-tiled transpose)
// ---------------------------------------------------------------------------
__global__ __launch_bounds__(256) void splitT_kernel(
    const float* __restrict__ in, u16* __restrict__ oh, u16* __restrict__ ol) {
  int n = blockIdx.z;
  int c0 = blockIdx.y * 32;
  int s0 = blockIdx.x * 32;
  __shared__ float tile[32][33];
  int tc = threadIdx.x & 31;   // s-offset on read / c-offset on write
  int tr = threadIdx.x >> 5;   // 8 rows per pass
#pragma unroll
  for (int i = 0; i < 4; ++i) {
    int c = c0 + tr + i * 8;
    int s = s0 + tc;
    tile[tr + i * 8][tc] = (s < S_) ? in[((size_t)n * C_ + c) * S_ + s] : 0.f;
  }
  __syncthreads();
#pragma unroll
  for (int i = 0; i < 4; ++i) {
    int s = s0 + tr + i * 8;
    if (s < S_) {
      float v = tile[tc][tr + i * 8];
      size_t o = ((size_t)n * S_ + s) * C_ + c0 + tc;
      u16 h, l; split2(v, h, l);
      oh[o] = h; ol[o] = l;
    }
  }
}

// ---------------------------------------------------------------------------
// plain weight split: W[i] -> hi/lo
// ---------------------------------------------------------------------------
__global__ __launch_bounds__(256) void splitw(const float* __restrict__ in,
                                              u16* __restrict__ oh,
                                              u16* __restrict__ ol, int nelem) {
  int i = blockIdx.x * 256 + threadIdx.x;
  if (i < nelem) { u16 h, l; split2(in[i], h, l); oh[i] = h; ol[i] = l; }
}

// ---------------------------------------------------------------------------
// pa weight repack+split: [co][ci][ky][kx] -> [co][ky*3+kx][ci] hi/lo
// ---------------------------------------------------------------------------
__global__ __launch_bounds__(256) void splitpa(const float* __restrict__ in,
                                               u16* __restrict__ oh,
                                               u16* __restrict__ ol) {
  int i = blockIdx.x * 256 + threadIdx.x;        // over 512*9*512
  if (i >= 512 * 9 * 512) return;
  int ci = i & 511;
  int r = i >> 9;              // co*9 + kp
  int co = r / 9, kp = r - co * 9;
  float v = in[(((size_t)co * 512 + ci) * 9) + kp];
  u16 h, l; split2(v, h, l); oh[i] = h; ol[i] = l;
}

// ---------------------------------------------------------------------------
// K1: adaptive avg pools to 1/2/3/6 (reads NCHW feats)
// ---------------------------------------------------------------------------
__global__ __launch_bounds__(256) void pool_kernel(const float* __restrict__ feats,
                                                   float* __restrict__ p0) {
  int nc = blockIdx.x;
  int n = nc >> 9, c = nc & 511;
  const float* plane = feats + (size_t)nc * S_;
  __shared__ float partial[396];
  for (int u = threadIdx.x; u < 396; u += 256) {
    const float* r = plane + u * 15;
    float s = 0.f;
#pragma unroll
    for (int i = 0; i < 15; ++i) s += r[i];
    partial[u] = s;
  }
  __syncthreads();
  __shared__ float sums6[36];
  if (threadIdx.x < 36) {
    int by = threadIdx.x / 6, bx = threadIdx.x % 6;
    float s = 0.f;
#pragma unroll
    for (int r = 0; r < 11; ++r) s += partial[(by * 11 + r) * 6 + bx];
    sums6[threadIdx.x] = s;
  }
  __syncthreads();
  int t = threadIdx.x;
  size_t base = (size_t)n * 50 * 512 + c;
  if (t < 36) {
    p0[base + (size_t)(14 + t) * 512] = sums6[t] * (1.0f / 165.0f);
  } else if (t < 45) {
    int i = t - 36; int y = i / 3, x = i % 3;
    float s = sums6[(2*y)*6 + 2*x] + sums6[(2*y)*6 + 2*x + 1]
            + sums6[(2*y+1)*6 + 2*x] + sums6[(2*y+1)*6 + 2*x + 1];
    p0[base + (size_t)(5 + i) * 512] = s * (1.0f / 660.0f);
  } else if (t < 49) {
    int i = t - 45; int y = i / 2, x = i % 2;
    float s = 0.f;
#pragma unroll
    for (int yy = 0; yy < 3; ++yy)
#pragma unroll
      for (int xx = 0; xx < 3; ++xx) s += sums6[(3*y + yy)*6 + 3*x + xx];
    p0[base + (size_t)(1 + i) * 512] = s * (1.0f / 1485.0f);
  } else if (t == 49) {
    float s = 0.f;
#pragma unroll
    for (int i = 0; i < 36; ++i) s += sums6[i];
    p0[base] = s * (1.0f / 5940.0f);
  }
}

// ---------------------------------------------------------------------------
// K2: tiny per-row GEMM: Out[rid][co] = sum_ci W[co][ci] * In[rid][ci]
// ---------------------------------------------------------------------------
__global__ __launch_bounds__(256) void rowgemm(const float* __restrict__ Wm,
                                               const float* __restrict__ In,
                                               float* __restrict__ Out,
                                               int off, int cnt) {
  int b = blockIdx.x;
  int n = b / cnt, j = b % cnt;
  size_t rid = (size_t)n * 50 + off + j;
  __shared__ __align__(16) float xin[512];
  xin[threadIdx.x]       = In[rid * 512 + threadIdx.x];
  xin[threadIdx.x + 256] = In[rid * 512 + 256 + threadIdx.x];
  __syncthreads();
  int co0 = threadIdx.x, co1 = threadIdx.x + 256;
  float acc0 = 0.f, acc1 = 0.f;
  for (int ci = 0; ci < 512; ci += 4) {
    float4 xv = *(const float4*)&xin[ci];
    float4 w0 = *(const float4*)&Wm[(size_t)co0 * 512 + ci];
    float4 w1 = *(const float4*)&Wm[(size_t)co1 * 512 + ci];
    acc0 += w0.x*xv.x + w0.y*xv.y + w0.z*xv.z + w0.w*xv.w;
    acc1 += w1.x*xv.x + w1.y*xv.y + w1.z*xv.z + w1.w*xv.w;
  }
  Out[rid * 512 + co0] = acc0;
  Out[rid * 512 + co1] = acc1;
}

// ---------------------------------------------------------------------------
// MFMA 1x1-conv GEMM, split-bf16 3-pass. Out[n][s][co] (T layout).
// OUT: 0 = f32 T, 1 = bf16 hi/lo T, 2 = f32 NCHW (d_out). SPLIT: K=1024 concat.
// Tile 64co x 64s, 4 waves of 32x32, K-step 32, global_load_lds staging.
// ---------------------------------------------------------------------------
template<int OUT, bool RELU, bool SPLIT>
__global__ __launch_bounds__(256) void gemmT(
    const u16* __restrict__ Wh, const u16* __restrict__ Wl,
    const u16* __restrict__ Xh, const u16* __restrict__ Xl,
    const u16* __restrict__ X2h, const u16* __restrict__ X2l,
    const float* __restrict__ bias,
    float* __restrict__ OutF, u16* __restrict__ OutH, u16* __restrict__ OutL,
    const u16* __restrict__ zb, int K) {
  __shared__ u16 Ah[2048], Al[2048], Bh[2048], Bl[2048];
  int t = threadIdx.x;
  int co0 = blockIdx.x * 64, s0 = blockIdx.y * 64, n = blockIdx.z;
  int wv = t >> 6, lane = t & 63;
  int wm = (wv >> 1) << 5, wn = (wv & 1) << 5;
  int fr = lane & 15, fg = lane >> 4;
  int arow = t >> 2, ach = t & 3;

  const size_t wrow = (size_t)(co0 + arow) * K + ach * 8;
  int s = s0 + arow;
  bool sv = s < S_;
  size_t xrow = ((size_t)n * S_ + (sv ? s : 0)) * 512 + ach * 8;

  f32x4 acc[2][2];
#pragma unroll
  for (int mi = 0; mi < 2; ++mi)
#pragma unroll
    for (int ni = 0; ni < 2; ++ni) acc[mi][ni] = f32x4{0.f, 0.f, 0.f, 0.f};

  for (int k0 = 0; k0 < K; k0 += 32) {
    const u16 *xh, *xl; int kk;
    if (SPLIT && k0 >= 512) { xh = X2h; xl = X2l; kk = k0 - 512; }
    else { xh = Xh; xl = Xl; kk = k0; }
    glds16(Wh + wrow + k0, &Ah[wv << 9]);
    glds16(Wl + wrow + k0, &Al[wv << 9]);
    glds16(sv ? xh + xrow + kk : (const u16*)zb, &Bh[wv << 9]);
    glds16(sv ? xl + xrow + kk : (const u16*)zb, &Bl[wv << 9]);
    __syncthreads();
    bf16x8 ah[2], al[2], bh[2], bl[2];
#pragma unroll
    for (int mi = 0; mi < 2; ++mi) {
      int r = (wm + mi * 16 + fr) * 32 + fg * 8;
      ah[mi] = *(const bf16x8*)&Ah[r];
      al[mi] = *(const bf16x8*)&Al[r];
    }
#pragma unroll
    for (int ni = 0; ni < 2; ++ni) {
      int r = (wn + ni * 16 + fr) * 32 + fg * 8;
      bh[ni] = *(const bf16x8*)&Bh[r];
      bl[ni] = *(const bf16x8*)&Bl[r];
    }
#pragma unroll
    for (int mi = 0; mi < 2; ++mi)
#pragma unroll
      for (int ni = 0; ni < 2; ++ni) {
        f32x4 c = acc[mi][ni];
        c = mfma16(al[mi], bh[ni], c);
        c = mfma16(ah[mi], bl[ni], c);
        c = mfma16(ah[mi], bh[ni], c);
        acc[mi][ni] = c;
      }
    __syncthreads();
  }

  int cob = co0 + wm + (fg << 2);
#pragma unroll
  for (int mi = 0; mi < 2; ++mi) {
    int com = cob + mi * 16;
    float4 bv = *(const float4*)&bias[com];
#pragma unroll
    for (int ni = 0; ni < 2; ++ni) {
      int sc = s0 + wn + ni * 16 + fr;
      if (sc >= S_) continue;
      f32x4 v = acc[mi][ni];
      float o0 = v[0] + bv.x, o1 = v[1] + bv.y, o2 = v[2] + bv.z, o3 = v[3] + bv.w;
      if (RELU) {
        o0 = fmaxf(o0, 0.f); o1 = fmaxf(o1, 0.f);
        o2 = fmaxf(o2, 0.f); o3 = fmaxf(o3, 0.f);
      }
      if (OUT == 0) {
        *(float4*)&OutF[((size_t)n * S_ + sc) * 512 + com] =
            make_float4(o0, o1, o2, o3);
      } else if (OUT == 1) {
        size_t o = ((size_t)n * S_ + sc) * 512 + com;
        u16 h0,h1,h2,h3,l0,l1,l2,l3;
        split2(o0,h0,l0); split2(o1,h1,l1); split2(o2,h2,l2); split2(o3,h3,l3);
        *(uint2*)&OutH[o] = make_uint2(h0 | ((unsigned)h1 << 16), h2 | ((unsigned)h3 << 16));
        *(uint2*)&OutL[o] = make_uint2(l0 | ((unsigned)l1 << 16), l2 | ((unsigned)l3 << 16));
      } else {
        OutF[((size_t)n * 512 + com + 0) * S_ + sc] = o0;
        OutF[((size_t)n * 512 + com + 1) * S_ + sc] = o1;
        OutF[((size_t)n * 512 + com + 2) * S_ + sc] = o2;
        OutF[((size_t)n * 512 + com + 3) * S_ + sc] = o3;
      }
    }
  }
}

// ---------------------------------------------------------------------------
// MFMA 3x3 conv, implicit GEMM, NHWC bf16 hi/lo in/out. K = 9*512.
// W packed [co][ky*3+kx][ci]. OUT: 1 = bf16 hi/lo T, 0 = f32 T (theta).
// ---------------------------------------------------------------------------
template<int ST, int PAD, int OUT>
__global__ __launch_bounds__(256) void conv3T(
    const u16* __restrict__ Wh, const u16* __restrict__ Wl,
    const u16* __restrict__ Xh, const u16* __restrict__ Xl,
    const float* __restrict__ bias,
    float* __restrict__ OutF, u16* __restrict__ OutH, u16* __restrict__ OutL,
    const u16* __restrict__ zb, int IH, int IW, int OH, int OW) {
  const int K = 4608;
  int P = OH * OW;
  __shared__ u16 Ah[2048], Al[2048], Bh[2048], Bl[2048];
  int t = threadIdx.x;
  int co0 = blockIdx.x * 64, p0b = blockIdx.y * 64, n = blockIdx.z;
  int wv = t >> 6, lane = t & 63;
  int wm = (wv >> 1) << 5, wn = (wv & 1) << 5;
  int fr = lane & 15, fg = lane >> 4;
  int arow = t >> 2, ach = t & 3;

  const size_t wrow = (size_t)(co0 + arow) * K + ach * 8;
  int p = p0b + arow;
  bool pvalid = p < P;
  int oy = p / OW, ox = p - (p / OW) * OW;

  f32x4 acc[2][2];
#pragma unroll
  for (int mi = 0; mi < 2; ++mi)
#pragma unroll
    for (int ni = 0; ni < 2; ++ni) acc[mi][ni] = f32x4{0.f, 0.f, 0.f, 0.f};

  for (int k0 = 0; k0 < K; k0 += 32) {
    int kt = k0 >> 5;
    int kp = kt >> 4, ci0 = (kt & 15) << 5;
    int ky = (kp >= 6) ? 2 : (kp >= 3 ? 1 : 0);
    int kx = kp - ky * 3;
    int iy = oy * ST + ky - PAD, ix = ox * ST + kx - PAD;
    bool ok = pvalid && (unsigned)iy < (unsigned)IH && (unsigned)ix < (unsigned)IW;
    size_t xoff = (((size_t)n * IH * IW + iy * IW + ix) << 9) + ci0 + (ach << 3);
    glds16(Wh + wrow + k0, &Ah[wv << 9]);
    glds16(Wl + wrow + k0, &Al[wv << 9]);
    glds16(ok ? Xh + xoff : (const u16*)zb, &Bh[wv << 9]);
    glds16(ok ? Xl + xoff : (const u16*)zb, &Bl[wv << 9]);
    __syncthreads();
    bf16x8 ah[2], al[2], bh[2], bl[2];
#pragma unroll
    for (int mi = 0; mi < 2; ++mi) {
      int r = (wm + mi * 16 + fr) * 32 + fg * 8;
      ah[mi] = *(const bf16x8*)&Ah[r];
      al[mi] = *(const bf16x8*)&Al[r];
    }
#pragma unroll
    for (int ni = 0; ni < 2; ++ni) {
      int r = (wn + ni * 16 + fr) * 32 + fg * 8;
      bh[ni] = *(const bf16x8*)&Bh[r];
      bl[ni] = *(const bf16x8*)&Bl[r];
    }
#pragma unroll
    for (int mi = 0; mi < 2; ++mi)
#pragma unroll
      for (int ni = 0; ni < 2; ++ni) {
        f32x4 c = acc[mi][ni];
        c = mfma16(al[mi], bh[ni], c);
        c = mfma16(ah[mi], bl[ni], c);
        c = mfma16(ah[mi], bh[ni], c);
        acc[mi][ni] = c;
      }
    __syncthreads();
  }

  int cob = co0 + wm + (fg << 2);
#pragma unroll
  for (int mi = 0; mi < 2; ++mi) {
    int com = cob + mi * 16;
    float4 bv = *(const float4*)&bias[com];
#pragma unroll
    for (int ni = 0; ni < 2; ++ni) {
      int pc = p0b + wn + ni * 16 + fr;
      if (pc >= P) continue;
      f32x4 v = acc[mi][ni];
      float o0 = v[0] + bv.x, o1 = v[1] + bv.y, o2 = v[2] + bv.z, o3 = v[3] + bv.w;
      if (OUT == 1) {
        size_t o = ((size_t)n * P + pc) * 512 + com;
        u16 h0,h1,h2,h3,l0,l1,l2,l3;
        split2(o0,h0,l0); split2(o1,h1,l1); split2(o2,h2,l2); split2(o3,h3,l3);
        *(uint2*)&OutH[o] = make_uint2(h0 | ((unsigned)h1 << 16), h2 | ((unsigned)h3 << 16));
        *(uint2*)&OutL[o] = make_uint2(l0 | ((unsigned)l1 << 16), l2 | ((unsigned)l3 << 16));
      } else {
        *(float4*)&OutF[((size_t)n * P + pc) * 512 + com] =
            make_float4(o0, o1, o2, o3);
      }
    }
  }
}

// ---------------------------------------------------------------------------
// fused parsing, T layout, c-coalesced. Same math as R1 (passed).
// ---------------------------------------------------------------------------
__global__ __launch_bounds__(256) void parsingT(
    const float* __restrict__ convF, const float* __restrict__ p,
    const float* __restrict__ q, u16* __restrict__ outH, u16* __restrict__ outL) {
  int n = blockIdx.y;
  int idx = blockIdx.x * 256 + threadIdx.x;   // over S_*512
  int c = idx & 511, s = idx >> 9;
  int h = s / 90, w = s - (s / 90) * 90;
  size_t gidx = ((size_t)n * S_ + s) * 512 + c;
  float cf = convF[gidx];
  const int szs[4]  = {1, 2, 3, 6};
  const int offs[4] = {0, 1, 5, 14};
  float num = 0.f, den = 0.f;
#pragma unroll
  for (int i = 0; i < 4; ++i) {
    int sz = szs[i];
    float fy = ((h + 0.5f) * sz) / 66.0f - 0.5f;
    float fl = floorf(fy);
    float tyf = fy - fl;
    int y0 = (int)fl;
    int y1 = min(y0 + 1, sz - 1);
    y0 = max(y0, 0);
    float fx = ((w + 0.5f) * sz) / 90.0f - 0.5f;
    float flx = floorf(fx);
    float txf = fx - flx;
    int x0 = (int)flx;
    int x1 = min(x0 + 1, sz - 1);
    x0 = max(x0, 0);
    size_t base = ((size_t)n * 50 + offs[i]) * 512 + c;
    int i00 = (y0 * sz + x0) * 512, i01 = (y0 * sz + x1) * 512;
    int i10 = (y1 * sz + x0) * 512, i11 = (y1 * sz + x1) * 512;
    float p00 = p[base + i00], p01 = p[base + i01];
    float p10 = p[base + i10], p11 = p[base + i11];
    float up = (p00 * (1.f - txf) + p01 * txf) * (1.f - tyf)
             + (p10 * (1.f - txf) + p11 * txf) * tyf;
    float q00 = q[base + i00], q01 = q[base + i01];
    float q10 = q[base + i10], q11 = q[base + i11];
    float qup = (q00 * (1.f - txf) + q01 * txf) * (1.f - tyf)
              + (q10 * (1.f - txf) + q11 * txf) * tyf;
    float wgt = 1.0f / (1.0f + expf(-(cf - qup)));
    num += up * wgt;
    den += wgt;
  }
  float r = num / den;
  u16 hh, ll; split2(r, hh, ll);
  outH[gidx] = hh; outL[gidx] = ll;
}

// ---------------------------------------------------------------------------
// VALID maxpool on NHWC bf16 hi/lo
// ---------------------------------------------------------------------------
__global__ __launch_bounds__(256) void maxpoolT(
    const u16* __restrict__ inH, const u16* __restrict__ inL,
    u16* __restrict__ outH, u16* __restrict__ outL,
    int IH, int IW, int OH, int OW, int k, int st) {
  int n = blockIdx.y;
  int idx = blockIdx.x * 256 + threadIdx.x;   // over OH*OW*512
  int c = idx & 511, pp = idx >> 9;
  int oy = pp / OW, ox = pp - (pp / OW) * OW;
  float m = -INFINITY;
  for (int ky = 0; ky < k; ++ky)
    for (int kx = 0; kx < k; ++kx) {
      size_t o = ((size_t)n * IH * IW + (oy * st + ky) * IW + ox * st + kx) * 512 + c;
      m = fmaxf(m, bf16_f(inH[o]) + bf16_f(inL[o]));
    }
  size_t o = ((size_t)n * OH * OW + pp) * 512 + c;
  u16 hh, ll; split2(m, hh, ll);
  outH[o] = hh; outL[o] = ll;
}

// ---------------------------------------------------------------------------
// dynamic depthwise 5x7, NHWC. inp f32 T, theta f32 [n][35][c], out bf16 hi/lo T
// ---------------------------------------------------------------------------
__global__ __launch_bounds__(256) void dynconvT(
    const float* __restrict__ inp, const float* __restrict__ theta,
    u16* __restrict__ outH, u16* __restrict__ outL) {
  int n = blockIdx.z, oy = blockIdx.y, c0 = blockIdx.x * 64;
  int tc = threadIdx.x & 63, tg = threadIdx.x >> 6;
  __shared__ float th[35][64];
  for (int j = tg; j < 35; j += 4)
    th[j][tc] = theta[((size_t)n * 35 + j) * 512 + c0 + tc];
  __syncthreads();
  int c = c0 + tc;
  for (int ox = tg; ox < 90; ox += 4) {
    float acc = 0.f;
#pragma unroll
    for (int ky = 0; ky < 5; ++ky) {
      int iy = oy + ky - 2;
      if ((unsigned)iy >= (unsigned)H_) continue;
#pragma unroll
      for (int kx = 0; kx < 7; ++kx) {
        int ix = ox + kx - 3;
        if ((unsigned)ix >= (unsigned)W_) continue;
        acc = fmaf(th[ky * 7 + kx][tc],
                   inp[((size_t)n * S_ + iy * 90 + ix) * 512 + c], acc);
      }
    }
    size_t o = ((size_t)n * S_ + oy * 90 + ox) * 512 + c;
    u16 hh, ll; split2(acc, hh, ll);
    outH[o] = hh; outL[o] = ll;
  }
}

// ---------------------------------------------------------------------------
extern "C" void kernel_launch(void* const* d_in, const int* in_sizes, int n_in,
                              void* d_out, int out_size, void* d_ws, size_t ws_size,
                              hipStream_t stream) {
  const float* feats  = (const float*)d_in[0];
  const float* scale_w= (const float*)d_in[1];
  const float* wn_w   = (const float*)d_in[2];
  const float* wn_b   = (const float*)d_in[3];
  const float* pa_w1  = (const float*)d_in[4];
  const float* pa_b1  = (const float*)d_in[5];
  const float* pa_w2  = (const float*)d_in[6];
  const float* pa_b2  = (const float*)d_in[7];
  const float* pa_w3  = (const float*)d_in[8];
  const float* pa_b3  = (const float*)d_in[9];
  const float* u_w    = (const float*)d_in[10];
  const float* u_b    = (const float*)d_in[11];
  const float* v_w    = (const float*)d_in[12];
  const float* v_b    = (const float*)d_in[13];
  const float* bott_w = (const float*)d_in[14];
  const float* bott_b = (const float*)d_in[15];

  char* wp = (char*)d_ws;
  auto nxt = [&](size_t bytes) {
    char* p = wp; wp += (bytes + 255) & ~(size_t)255; return p;
  };
  const size_t BIGE = (size_t)N_ * C_ * S_;   // 24,330,240
  u16* fH   = (u16*)nxt(BIGE * 2);
  u16* fL   = (u16*)nxt(BIGE * 2);
  float* ws2f = (float*)nxt(BIGE * 4);        // convF -> inp -> pose(h/l)
  u16* ws2h = (u16*)ws2f; u16* ws2l = ws2h + BIGE;
  float* ws3f = (float*)nxt(BIGE * 4);        // parsing(h/l) -> pose0(h/l)
  u16* ws3h = (u16*)ws3f; u16* ws3l = ws3h + BIGE;
  u16* wnH  = (u16*)nxt(262144 * 2); u16* wnL  = (u16*)nxt(262144 * 2);
  u16* uH   = (u16*)nxt(262144 * 2); u16* uL   = (u16*)nxt(262144 * 2);
  u16* vH   = (u16*)nxt(262144 * 2); u16* vL   = (u16*)nxt(262144 * 2);
  u16* boH  = (u16*)nxt(524288 * 2); u16* boL  = (u16*)nxt(524288 * 2);
  const size_t PAE = (size_t)512 * 9 * 512;   // 2,359,296
  u16* pa1H = (u16*)nxt(PAE * 2); u16* pa1L = (u16*)nxt(PAE * 2);
  u16* pa2H = (u16*)nxt(PAE * 2); u16* pa2L = (u16*)nxt(PAE * 2);
  u16* pa3H = (u16*)nxt(PAE * 2); u16* pa3L = (u16*)nxt(PAE * 2);
  const size_t T1E = (size_t)N_ * 1408 * 512;
  const size_t T2E = (size_t)N_ * 352 * 512;
  const size_t T4E = (size_t)N_ * 35 * 512;
  u16* t1H = (u16*)nxt(T1E * 2); u16* t1L = (u16*)nxt(T1E * 2);
  u16* t2H = (u16*)nxt(T2E * 2); u16* t2L = (u16*)nxt(T2E * 2);
  u16* t3H = (u16*)nxt(T2E * 2); u16* t3L = (u16*)nxt(T2E * 2);
  u16* t4H = (u16*)nxt(T4E * 2); u16* t4L = (u16*)nxt(T4E * 2);
  float* thetaF = (float*)nxt(T4E * 4);
  float* p0   = (float*)nxt((size_t)N_ * 50 * 512 * 4);
  float* pbuf = (float*)nxt((size_t)N_ * 50 * 512 * 4);
  float* qbuf = (float*)nxt((size_t)N_ * 50 * 512 * 4);
  u16* zb = (u16*)nxt(256);
  float* outp = (float*)d_out;

  // --- prep
  zerok<<<1, 128, 0, stream>>>(zb);
  splitT_kernel<<<dim3(186, 16, N_), 256, 0, stream>>>(feats, fH, fL);
  splitw<<<1024, 256, 0, stream>>>(wn_w, wnH, wnL, 262144);
  splitw<<<1024, 256, 0, stream>>>(u_w, uH, uL, 262144);
  splitw<<<1024, 256, 0, stream>>>(v_w, vH, vL, 262144);
  splitw<<<2048, 256, 0, stream>>>(bott_w, boH, boL, 524288);
  splitpa<<<9216, 256, 0, stream>>>(pa_w1, pa1H, pa1L);
  splitpa<<<9216, 256, 0, stream>>>(pa_w2, pa2H, pa2L);
  splitpa<<<9216, 256, 0, stream>>>(pa_w3, pa3H, pa3L);

  // --- pools + tiny gemms
  pool_kernel<<<dim3(N_ * C_), 256, 0, stream>>>(feats, p0);
  const int offs[4] = {0, 1, 5, 14};
  const int cnts[4] = {1, 4, 9, 36};
  for (int i = 0; i < 4; ++i)
    rowgemm<<<dim3(N_ * cnts[i]), 256, 0, stream>>>(
        scale_w + (size_t)i * C_ * C_, p0, pbuf, offs[i], cnts[i]);
  rowgemm<<<dim3(N_ * 50), 256, 0, stream>>>(wn_w, pbuf, qbuf, 0, 50);

  // --- convF = wn*feats + b -> ws2f (f32 T)
  gemmT<0, false, false><<<dim3(8, 93, N_), 256, 0, stream>>>(
      wnH, wnL, fH, fL, nullptr, nullptr, wn_b, ws2f, nullptr, nullptr, zb, 512);
  // --- parsing -> ws3 h/l
  parsingT<<<dim3(11880, N_), 256, 0, stream>>>(ws2f, pbuf, qbuf, ws3h, ws3l);
  // --- inp = u*feats + b -> ws2f (f32 T)  (convF dead)
  gemmT<0, false, false><<<dim3(8, 93, N_), 256, 0, stream>>>(
      uH, uL, fH, fL, nullptr, nullptr, u_b, ws2f, nullptr, nullptr, zb, 512);
  // --- pa chain
  conv3T<2, 0, 1><<<dim3(8, 22, N_), 256, 0, stream>>>(
      pa1H, pa1L, ws3h, ws3l, pa_b1, nullptr, t1H, t1L, zb, 66, 90, 32, 44);
  maxpoolT<<<dim3(704, N_), 256, 0, stream>>>(t1H, t1L, t2H, t2L,
                                              32, 44, 16, 22, 2, 2);
  conv3T<1, 1, 1><<<dim3(8, 6, N_), 256, 0, stream>>>(
      pa2H, pa2L, t2H, t2L, pa_b2, nullptr, t3H, t3L, zb, 16, 22, 16, 22);
  maxpoolT<<<dim3(70, N_), 256, 0, stream>>>(t3H, t3L, t4H, t4L,
                                             16, 22, 5, 7, 3, 3);
  conv3T<1, 1, 0><<<dim3(8, 1, N_), 256, 0, stream>>>(
      pa3H, pa3L, t4H, t4L, pa_b3, thetaF, nullptr, nullptr, zb, 5, 7, 5, 7);
  // --- pose0 = dynconv(inp, theta) -> ws3 h/l (parsing dead)
  dynconvT<<<dim3(8, 66, N_), 256, 0, stream>>>(ws2f, thetaF, ws3h, ws3l);
  // --- pose = relu(v*pose0 + b) -> ws2 h/l (inp dead)
  gemmT<1, true, false><<<dim3(8, 93, N_), 256, 0, stream>>>(
      vH, vL, ws3h, ws3l, nullptr, nullptr, v_b, nullptr, ws2h, ws2l, zb, 512);
  // --- out = relu(bott*[pose|feats] + b) -> d_out (NCHW)
  gemmT<2, true, true><<<dim3(8, 93, N_), 256, 0, stream>>>(
      boH, boL, ws2h, ws2l, fH, fL, bott_b, outp, nullptr, nullptr, zb, 1024);
}